// Round 3
// baseline (411.539 us; speedup 1.0000x reference)
//
#include <hip/hip_runtime.h>
#include <math.h>

#define NROWS 65536
#define BN_EPS 1e-5f
#define MBLK   512    // main-kernel grid: 128 rows per block, 2 rows/thread
#define TSTR   1024   // ws_blkT stride: colsums idx=blk (<512), BN idx=blk*2+set (<1024)

// ---- workspace layout (floats) ----
// OFF_PARTIAL : per-row partial                                        [65536]
// OFF_H       : h[row*8+j]                                             [524288]
// OFF_REC     : packed per-feature record rec[f][84]                   [5376]
//               0..15 U=W1+W2 | 16..31 B1 | 32..47 B2 | 48..55 A1
//               56..63 A2 | 64..71 A3 | 72 QU 73 QB1 74 QB2 75 2QUB1
//               76 2QUB2 77 2QB1B2 | 78 w1 79 b1 80 b2 | 81..83 pad
// OFF_BLKT    : per-block stats transposed blkT[v*1024+idx], v<80      [81920]
//               v 0..63 Xc colsum (idx=blk, 512 valid)
//               v 64..71 sum h_j, 72..79 sum h_j^2 (idx=blk*2+set, 1024 valid)
// OFF_T       : reduced totals                                         [96]
#define OFF_PARTIAL 0
#define OFF_H       65536
#define OFF_REC     589824
#define OFF_BLKT    595200
#define OFF_T       677120

// 64 blocks x 64 threads: block f builds rec[f][*].  (proven R4-R11)
__global__ __launch_bounds__(64) void precompute_kernel(
    const float* __restrict__ W1, const float* __restrict__ B1,
    const float* __restrict__ W2, const float* __restrict__ B2,
    const float* __restrict__ lin1_w, const float* __restrict__ w1,
    const float* __restrict__ b1, const float* __restrict__ b2,
    float* __restrict__ rec)
{
    int f = blockIdx.x, t = threadIdx.x;
    __shared__ float u[16], x[16], y[16];
    if (t < 16) {
        float uu = W1[f * 16 + t] + W2[f * 16 + t];
        float xx = B1[f * 16 + t];
        float yy = B2[f * 16 + t];
        u[t] = uu; x[t] = xx; y[t] = yy;
        rec[f * 84 + t]      = uu;
        rec[f * 84 + 16 + t] = xx;
        rec[f * 84 + 32 + t] = yy;
    }
    __syncthreads();
    if (t < 24) {
        int j = t & 7, which = t >> 3;
        const float* src = (which == 0) ? u : (which == 1) ? x : y;
        const float* lw = lin1_w + j * 1024 + f * 16;
        float acc = 0.f;
#pragma unroll
        for (int e = 0; e < 16; e++) acc = fmaf(src[e], lw[e], acc);
        rec[f * 84 + 48 + which * 8 + j] = acc;
    } else if (t < 30) {
        int q = t - 24;
        const float* s1 = (q == 0 || q == 3 || q == 4) ? u : (q == 1 || q == 5) ? x : y;
        const float* s2 = (q == 0) ? u : (q == 1 || q == 3) ? x : y;
        float acc = 0.f;
#pragma unroll
        for (int e = 0; e < 16; e++) acc = fmaf(s1[e], s2[e], acc);
        rec[f * 84 + 72 + q] = (q < 3 ? 1.f : 2.f) * acc;
    } else if (t == 30) {
        rec[f * 84 + 78] = w1[f];
        rec[f * 84 + 79] = b1[f];
        rec[f * 84 + 80] = b2[f];
        rec[f * 84 + 81] = 0.f;
        rec[f * 84 + 82] = 0.f;
        rec[f * 84 + 83] = 0.f;
    }
}

// One f-iteration of the hot loop. I is a compile-time literal; AVx/CVx are
// scalar float components of the chunk's float4 buffers. cs[I] static index.
#define FITER(I, AV0, CV0, AV1, CV1) do {                                   \
    const float* r = recw + (I) * 84;   /* wave-uniform -> LDS broadcast */ \
    float a0 = (AV0), c0 = (CV0), a1 = (AV1), c1 = (CV1);                   \
    float pp0 = a0 * c0, pp1 = a1 * c1;                                     \
    float rw1 = r[78], rb1 = r[79], rb2 = r[80];                            \
    p1_0  = fmaf(fmaf(rw1, a0, rb1), c0, p1_0);                             \
    p1_1  = fmaf(fmaf(rw1, a1, rb1), c1, p1_1);                             \
    p2a_0 = fmaf(a0, rb2, p2a_0);                                           \
    p2a_1 = fmaf(a1, rb2, p2a_1);                                           \
    float q0 = r[72], q1 = r[73], q2 = r[74];                               \
    float q3 = r[75], q4 = r[76], q5 = r[77];                               \
    q_0 = fmaf(pp0 * pp0, q0, q_0);  q_0 = fmaf(c0 * c0, q1, q_0);          \
    q_0 = fmaf(a0 * a0,   q2, q_0);  q_0 = fmaf(pp0 * c0, q3, q_0);         \
    q_0 = fmaf(pp0 * a0,  q4, q_0);  q_0 = fmaf(pp0,      q5, q_0);         \
    q_1 = fmaf(pp1 * pp1, q0, q_1);  q_1 = fmaf(c1 * c1, q1, q_1);          \
    q_1 = fmaf(a1 * a1,   q2, q_1);  q_1 = fmaf(pp1 * c1, q3, q_1);         \
    q_1 = fmaf(pp1 * a1,  q4, q_1);  q_1 = fmaf(pp1,      q5, q_1);         \
    _Pragma("unroll")                                                       \
    for (int e = 0; e < 16; e++) {                                          \
        float u = r[e], x = r[16 + e], y = r[32 + e];                       \
        s[e]  = fmaf(pp0, u, fmaf(c0, x, fmaf(a0, y, s[e])));               \
        s2[e] = fmaf(pp1, u, fmaf(c1, x, fmaf(a1, y, s2[e])));              \
    }                                                                       \
    _Pragma("unroll")                                                       \
    for (int j = 0; j < 8; j++) {                                           \
        float w1c = r[48 + j], w2c = r[56 + j], w3c = r[64 + j];            \
        hh[j]  = fmaf(pp0, w1c, fmaf(c0, w2c, fmaf(a0, w3c, hh[j])));       \
        hh2[j] = fmaf(pp1, w1c, fmaf(c1, w2c, fmaf(a1, w3c, hh2[j])));      \
    }                                                                       \
    cs[I] = c0 + c1;                                                        \
} while (0)

#define CHUNK(K, BA0, BC0, BA1, BC1)                                        \
    FITER(4*(K)+0, BA0.x, BC0.x, BA1.x, BC1.x);                             \
    FITER(4*(K)+1, BA0.y, BC0.y, BA1.y, BC1.y);                             \
    FITER(4*(K)+2, BA0.z, BC0.z, BA1.z, BC1.z);                             \
    FITER(4*(K)+3, BA0.w, BC0.w, BA1.w, BC1.w);

// 512 blocks x 256 threads, 2 rows/thread (rows row0, row0+64), 2 blk/CU.
// R2 falsified the LDS-issue theory: main is LATENCY-bound on the up-front
// Xa/Xc load blast (R2 @1 wave/SIMD: VALUBusy 12%, 0.78 TB/s). Fix here:
// software-pipeline the global loads -- 4 hand-unrolled chunks of 4 f-iters,
// chunk k+1's float4s prefetched into ping-pong named buffers during chunk
// k's ~1400cy of FMA (covers 900cy HBM miss). sched_barrier(0) at chunk
// seams stops R5's wholesale ds_read hoisting / VGPR explosion while leaving
// each prefetch textually ahead of its covering compute.
// All arrays statically indexed (rule #20). waves_per_eu(2,4) caps VGPR<=256.
// Colsum butterfly AFTER the hot loop (R10 lesson: shfl shares lgkmcnt).
__global__ __launch_bounds__(256)
__attribute__((amdgpu_waves_per_eu(2, 4)))
void main_kernel(
    const float* __restrict__ Xa, const float* __restrict__ Xc,
    const float* __restrict__ rec, const float* __restrict__ lin1_b,
    float* __restrict__ ws_partial, float* __restrict__ ws_h,
    float* __restrict__ ws_blkT)
{
    // [0,5376) = rec staging during phase B; then cmb[2][4][64][29] (aliased,
    // barrier-separated -- R4-proven pattern)
    __shared__ __align__(16) float smem[14848];

    int tid  = threadIdx.x;
    int lane = tid & 63;
    int wv   = tid >> 6;
    int wu   = __builtin_amdgcn_readfirstlane(wv);
    int blk  = blockIdx.x;
    int f0   = wu * 16;
    int row0 = blk * 128 + lane;
    int row1 = row0 + 64;

    const float4* pa0 = (const float4*)(Xa + (size_t)row0 * 64 + f0);
    const float4* pc0 = (const float4*)(Xc + (size_t)row0 * 64 + f0);
    const float4* pa1 = (const float4*)(Xa + (size_t)row1 * 64 + f0);
    const float4* pc1 = (const float4*)(Xc + (size_t)row1 * 64 + f0);

    // chunk 0 + chunk 1 issued before the barrier (land during staging wait)
    float4 bA0 = pa0[0], bC0 = pc0[0], bA1 = pa1[0], bC1 = pc1[0];
    float4 dA0 = pa0[1], dC0 = pc0[1], dA1 = pa1[1], dC1 = pc1[1];

    // stage rec -> LDS (coalesced float4, ~21.5 KB)
    {
        const float4* src = (const float4*)rec;
        float4* dst = (float4*)smem;
        for (int i = tid; i < 1344; i += 256) dst[i] = src[i];
    }
    __syncthreads();   // rec staged (drains vmcnt too -> chunks 0/1 landed)

    float s[16], s2[16], hh[8], hh2[8], cs[16];
#pragma unroll
    for (int e = 0; e < 16; e++) { s[e] = 0.f; s2[e] = 0.f; }
#pragma unroll
    for (int j = 0; j < 8; j++) { hh[j] = 0.f; hh2[j] = 0.f; }
    float p1_0 = 0.f, p2a_0 = 0.f, q_0 = 0.f;
    float p1_1 = 0.f, p2a_1 = 0.f, q_1 = 0.f;

    const float* recw = smem + f0 * 84;

    CHUNK(0, bA0, bC0, bA1, bC1);
    __builtin_amdgcn_sched_barrier(0);
    // prefetch chunk 2 into the b-buffers (chunk-0 values dead)
    bA0 = pa0[2]; bC0 = pc0[2]; bA1 = pa1[2]; bC1 = pc1[2];
    CHUNK(1, dA0, dC0, dA1, dC1);
    __builtin_amdgcn_sched_barrier(0);
    // prefetch chunk 3 into the d-buffers
    dA0 = pa0[3]; dC0 = pc0[3]; dA1 = pa1[3]; dC1 = pc1[3];
    CHUNK(2, bA0, bC0, bA1, bC1);
    __builtin_amdgcn_sched_barrier(0);
    CHUNK(3, dA0, dC0, dA1, dC1);

    // Xc column sums over this block's 128 rows (cs[i] = row0+row1 pre-sum)
    {
#pragma unroll
        for (int off = 1; off < 64; off <<= 1) {
#pragma unroll
            for (int i = 0; i < 16; i++) cs[i] += __shfl_xor(cs[i], off);
        }
        if (lane == 0) {
#pragma unroll
            for (int i = 0; i < 16; i++)
                ws_blkT[(size_t)(f0 + i) * TSTR + blk] = cs[i];
        }
    }

    // cross-wave combine (aliases rec region; barrier retires table reads)
    __syncthreads();
    {
        float* cmb0 = smem + (wv * 64 + lane) * 29;
        float* cmb1 = smem + 7424 + (wv * 64 + lane) * 29;
#pragma unroll
        for (int e = 0; e < 16; e++) { cmb0[e] = s[e]; cmb1[e] = s2[e]; }
#pragma unroll
        for (int j = 0; j < 8; j++) { cmb0[16 + j] = hh[j]; cmb1[16 + j] = hh2[j]; }
        cmb0[24] = p1_0;  cmb1[24] = p1_1;
        cmb0[25] = p2a_0; cmb1[25] = p2a_1;
        cmb0[26] = q_0;   cmb1[26] = q_1;
    }
    __syncthreads();

    if (tid < 128) {
        int set = tid >> 6;        // set 0: rows +0..63 (wave 0), set 1: rows +64..127 (wave 1)
        int l   = tid & 63;
        const float* base = smem + set * 7424;
        float S[16], H[8], P1 = 0.f, P2 = 0.f, Q = 0.f;
#pragma unroll
        for (int e = 0; e < 16; e++) S[e] = 0.f;
#pragma unroll
        for (int j = 0; j < 8; j++) H[j] = 0.f;
#pragma unroll
        for (int w = 0; w < 4; w++) {
            const float* c2 = base + (w * 64 + l) * 29;
#pragma unroll
            for (int e = 0; e < 16; e++) S[e] += c2[e];
#pragma unroll
            for (int j = 0; j < 8; j++) H[j] += c2[16 + j];
            P1 += c2[24];
            P2 += c2[25];
            Q  += c2[26];
        }
#pragma unroll
        for (int j = 0; j < 8; j++) H[j] += lin1_b[j];

        float ss = 0.f;
#pragma unroll
        for (int e = 0; e < 16; e++) ss = fmaf(S[e], S[e], ss);
        int rr = blk * 128 + set * 64 + l;
        ws_partial[rr] = (P1 + P2) * (1.f / 64.f) + (ss - Q) * (0.5f / 16.f);
        *(float4*)(ws_h + (size_t)rr * 8)     = make_float4(H[0], H[1], H[2], H[3]);
        *(float4*)(ws_h + (size_t)rr * 8 + 4) = make_float4(H[4], H[5], H[6], H[7]);

        // BN partials over this set's 64 rows (butterfly stays in-wave: set==wave)
        float bn[16];
#pragma unroll
        for (int j = 0; j < 8; j++) { bn[j] = H[j]; bn[8 + j] = H[j] * H[j]; }
#pragma unroll
        for (int off = 1; off < 64; off <<= 1) {
#pragma unroll
            for (int i = 0; i < 16; i++) bn[i] += __shfl_xor(bn[i], off);
        }
        if (l == 0) {
#pragma unroll
            for (int i = 0; i < 16; i++)
                ws_blkT[(size_t)(64 + i) * TSTR + blk * 2 + set] = bn[i];
        }
    }
}

// 80 waves: one per statistic. v<64 (colsums): 512 partials; v>=64 (BN): 1024.
__global__ __launch_bounds__(256) void reduce_kernel(
    const float* __restrict__ ws_blkT, float* __restrict__ T)
{
    int gtid = blockIdx.x * 256 + threadIdx.x;
    int v = gtid >> 6;
    int lane = gtid & 63;
    const float* p = ws_blkT + (size_t)v * TSTR + lane;
    float acc = 0.f;
    if (v < 64) {
#pragma unroll
        for (int k = 0; k < 8; k++) acc += p[k * 64];
    } else {
#pragma unroll
        for (int k = 0; k < 16; k++) acc += p[k * 64];
    }
#pragma unroll
    for (int off = 32; off; off >>= 1) acc += __shfl_xor(acc, off);
    if (lane == 0) T[v] = acc;
}

// 512 blocks x 256 threads: two threads per row. (R8-proven)
__global__ __launch_bounds__(256) void final_kernel(
    const float* __restrict__ Xa, const float* __restrict__ w2,
    const float* __restrict__ gamma, const float* __restrict__ beta,
    const float* __restrict__ lin2_w, const float* __restrict__ lin2_b,
    const float* __restrict__ T, const float* __restrict__ ws_partial,
    const float* __restrict__ ws_h, float* __restrict__ out)
{
    __shared__ float sg[64], sScale[8], sShift[8], sColw[8];
    __shared__ float sBsum;
    int tid = threadIdx.x;
    if (tid < 64) {
        sg[tid] = w2[tid] * (T[tid] * (1.f / 65536.f));
    } else if (tid < 72) {
        int j = tid - 64;
        float mu  = T[64 + j] * (1.f / 65536.f);
        float var = T[72 + j] * (1.f / 65536.f) - mu * mu;
        float sc = gamma[j] / sqrtf(var + BN_EPS);
        sScale[j] = sc;
        sShift[j] = beta[j] - mu * sc;
    } else if (tid < 80) {
        int j = tid - 72;
        sColw[j] = lin2_w[j] + lin2_w[8 + j] + lin2_w[16 + j] + lin2_w[24 + j];
    } else if (tid == 80) {
        sBsum = lin2_b[0] + lin2_b[1] + lin2_b[2] + lin2_b[3];
    }
    __syncthreads();

    int row  = (blockIdx.x * 256 + tid) >> 1;
    int half = tid & 1;
    int fo   = half * 32;

    const float4* xa4 = (const float4*)(Xa + (size_t)row * 64 + fo);
    float p2b = 0.f;
#pragma unroll
    for (int k = 0; k < 8; k++) {
        float4 vv = xa4[k];
        int b = fo + k * 4;
        p2b += vv.x * sg[b] + vv.y * sg[b + 1] + vv.z * sg[b + 2] + vv.w * sg[b + 3];
    }

    float4 hq = *(const float4*)(ws_h + (size_t)row * 8 + half * 4);
    float hv[4] = {hq.x, hq.y, hq.z, hq.w};
    float dmp = 0.f;
#pragma unroll
    for (int jj = 0; jj < 4; jj++) {
        int j = half * 4 + jj;
        float hn = tanhf(hv[jj] * sScale[j] + sShift[j]);
        dmp = fmaf(hn, sColw[j], dmp);
    }

    float val = p2b * (1.f / 64.f) + dmp * 0.25f;
    val += __shfl_xor(val, 1);
    if (!half)
        out[row] = val + ws_partial[row] + sBsum * 0.25f;
}

extern "C" void kernel_launch(void* const* d_in, const int* in_sizes, int n_in,
                              void* d_out, int out_size, void* d_ws, size_t ws_size,
                              hipStream_t stream) {
    const float* Xa        = (const float*)d_in[0];
    const float* Xc        = (const float*)d_in[1];
    const float* w1        = (const float*)d_in[2];
    const float* b1        = (const float*)d_in[3];
    const float* w2        = (const float*)d_in[4];
    const float* b2        = (const float*)d_in[5];
    const float* W1        = (const float*)d_in[6];
    const float* B1        = (const float*)d_in[7];
    const float* W2        = (const float*)d_in[8];
    const float* B2        = (const float*)d_in[9];
    const float* lin1_w    = (const float*)d_in[10];
    const float* lin1_b    = (const float*)d_in[11];
    const float* bn1_gamma = (const float*)d_in[12];
    const float* bn1_beta  = (const float*)d_in[13];
    const float* lin2_w    = (const float*)d_in[14];
    const float* lin2_b    = (const float*)d_in[15];

    float* ws  = (float*)d_ws;
    float* out = (float*)d_out;

    float* ws_partial = ws + OFF_PARTIAL;
    float* ws_h       = ws + OFF_H;
    float* ws_rec     = ws + OFF_REC;
    float* ws_blkT    = ws + OFF_BLKT;
    float* ws_T       = ws + OFF_T;

    precompute_kernel<<<64, 64, 0, stream>>>(W1, B1, W2, B2, lin1_w,
                                             w1, b1, b2, ws_rec);
    main_kernel<<<MBLK, 256, 0, stream>>>(Xa, Xc, ws_rec, lin1_b,
                                          ws_partial, ws_h, ws_blkT);
    reduce_kernel<<<20, 256, 0, stream>>>(ws_blkT, ws_T);
    final_kernel<<<512, 256, 0, stream>>>(Xa, w2, bn1_gamma, bn1_beta,
                                          lin2_w, lin2_b, ws_T,
                                          ws_partial, ws_h, out);
}

// Round 5
// 236.530 us; speedup vs baseline: 1.7399x; 1.7399x over previous
//
#include <hip/hip_runtime.h>
#include <math.h>

#define NROWS 65536
#define BN_EPS 1e-5f
#define MBLK   512    // fused grid: 128 rows per block, 2 rows/thread
#define TSTR   1024   // ws_blkT stride: colsums idx=blk (<512), BN idx=blk*2+set (<1024)

// ---- workspace layout (floats) ----
// OFF_REC  : packed per-feature record rec[f][84]                      [5376]
// OFF_BLKT : per-block stats transposed blkT[v*1024+idx], v<80        [81920]
//            v 0..63 Xc colsum (idx=blk, 512 valid)
//            v 64..71 sum h_j, 72..79 sum h_j^2 (idx=blk*2+set, 1024 valid)
// OFF_T    : reduced totals                                           [96]
// OFF_CNT  : grid-barrier counter (uint32)                            [1]
#define OFF_REC   589824
#define OFF_BLKT  595200
#define OFF_T     677120
#define OFF_CNT   677216

// 64 blocks x 64 threads: block f builds rec[f][*].  (proven R4-R11)
// Also zeroes the grid-barrier counter (runs before fused_kernel in-stream,
// after the harness workspace poison -> counter is fresh every iteration).
__global__ __launch_bounds__(64) void precompute_kernel(
    const float* __restrict__ W1, const float* __restrict__ B1,
    const float* __restrict__ W2, const float* __restrict__ B2,
    const float* __restrict__ lin1_w, const float* __restrict__ w1,
    const float* __restrict__ b1, const float* __restrict__ b2,
    float* __restrict__ rec, unsigned* __restrict__ cnt)
{
    int f = blockIdx.x, t = threadIdx.x;
    __shared__ float u[16], x[16], y[16];
    if (t < 16) {
        float uu = W1[f * 16 + t] + W2[f * 16 + t];
        float xx = B1[f * 16 + t];
        float yy = B2[f * 16 + t];
        u[t] = uu; x[t] = xx; y[t] = yy;
        rec[f * 84 + t]      = uu;
        rec[f * 84 + 16 + t] = xx;
        rec[f * 84 + 32 + t] = yy;
    }
    __syncthreads();
    if (t < 24) {
        int j = t & 7, which = t >> 3;
        const float* src = (which == 0) ? u : (which == 1) ? x : y;
        const float* lw = lin1_w + j * 1024 + f * 16;
        float acc = 0.f;
#pragma unroll
        for (int e = 0; e < 16; e++) acc = fmaf(src[e], lw[e], acc);
        rec[f * 84 + 48 + which * 8 + j] = acc;
    } else if (t < 30) {
        int q = t - 24;
        const float* s1 = (q == 0 || q == 3 || q == 4) ? u : (q == 1 || q == 5) ? x : y;
        const float* s2 = (q == 0) ? u : (q == 1 || q == 3) ? x : y;
        float acc = 0.f;
#pragma unroll
        for (int e = 0; e < 16; e++) acc = fmaf(s1[e], s2[e], acc);
        rec[f * 84 + 72 + q] = (q < 3 ? 1.f : 2.f) * acc;
    } else if (t == 30) {
        rec[f * 84 + 78] = w1[f];
        rec[f * 84 + 79] = b1[f];
        rec[f * 84 + 80] = b2[f];
        rec[f * 84 + 81] = 0.f;
        rec[f * 84 + 82] = 0.f;
        rec[f * 84 + 83] = 0.f;
    } else if (t == 31 && f == 0) {
        *cnt = 0u;   // grid-barrier counter reset (visible at next dispatch)
    }
}

// Manual grid barrier: AMD cooperative grid.sync() is exactly this pattern
// (atomic arrive + spin at AGENT scope); cooperative launch adds only a
// grid-size validation, which is what silently killed R4. Single counter,
// monotonic targets (512, then 1024) -> no reset/sense needed.
// Release: acq_rel RMW orders this block's prior global writes (L2 wb to the
// coherent LLC). Acquire: atomic spin load + post-barrier __threadfence()
// on ALL threads invalidates stale L1/L2 lines before non-atomic reads.
__device__ __forceinline__ void grid_barrier(unsigned* cnt, unsigned target)
{
    __syncthreads();
    if (threadIdx.x == 0) {
        __hip_atomic_fetch_add(cnt, 1u, __ATOMIC_ACQ_REL, __HIP_MEMORY_SCOPE_AGENT);
        while (__hip_atomic_load(cnt, __ATOMIC_ACQUIRE, __HIP_MEMORY_SCOPE_AGENT) < target) {
            __builtin_amdgcn_s_sleep(2);
        }
    }
    __syncthreads();
    __threadfence();
}

// Fused main+reduce+final. 512 blocks x 256 threads, 2 rows/thread.
// LDS = 29,696 B -> 2 blocks/CU guaranteed even under a conservative
// 64 KB/CU occupancy model (HW itself fit 2 blocks at 59 KB in R3), so all
// 512 blocks are co-resident and the manual barrier cannot deadlock.
// Phase 1 = R1's proven main loop VERBATIM (rolled; R3 lesson: any full
// f-unroll spills -> ~1 GB scratch traffic). Combine uses ONE 7424-float
// buffer sequentially (set 0, barrier, set 1) to stay under 32 KB.
// Phase 2 = 80-wave reduce on blocks 0..19 between grid barriers.
// Phase 3 = final math from registers: p2b rebuilt from a_/a2_ (kills
// final_kernel's 16 MB Xa re-read + launch); H[8]/rowPartial ride registers
// (kills ws_h/ws_partial HBM round-trips).
__global__ __launch_bounds__(256)
__attribute__((amdgpu_waves_per_eu(2, 4)))
void fused_kernel(
    const float* __restrict__ Xa, const float* __restrict__ Xc,
    const float* __restrict__ rec, const float* __restrict__ lin1_b,
    const float* __restrict__ w2, const float* __restrict__ gamma,
    const float* __restrict__ beta, const float* __restrict__ lin2_w,
    const float* __restrict__ lin2_b,
    float* __restrict__ ws_blkT, float* __restrict__ ws_T,
    unsigned* __restrict__ cnt, float* __restrict__ out)
{
    // [0,5376) rec staging; then cmb[4][64][29] (7424 floats, aliased,
    // barrier-separated); phase 3 reuses [0,1120).
    __shared__ __align__(16) float smem[7424];

    int tid  = threadIdx.x;
    int lane = tid & 63;
    int wv   = tid >> 6;
    int wu   = __builtin_amdgcn_readfirstlane(wv);
    int blk  = blockIdx.x;
    int f0   = wu * 16;
    int row0 = blk * 128 + lane;
    int row1 = row0 + 64;

    // stage rec -> LDS (coalesced float4, ~21.5 KB)
    {
        const float4* src = (const float4*)rec;
        float4* dst = (float4*)smem;
        for (int i = tid; i < 1344; i += 256) dst[i] = src[i];
    }

    // per-lane a/c for both rows (R7-proven layout; L1-hot scratch)
    const float4* pa0 = (const float4*)(Xa + (size_t)row0 * 64 + f0);
    const float4* pc0 = (const float4*)(Xc + (size_t)row0 * 64 + f0);
    const float4* pa1 = (const float4*)(Xa + (size_t)row1 * 64 + f0);
    const float4* pc1 = (const float4*)(Xc + (size_t)row1 * 64 + f0);
    float a_[16], c_[16], a2_[16], c2_[16];
#pragma unroll
    for (int k = 0; k < 4; k++) {
        float4 av = pa0[k], cv = pc0[k];
        a_[k * 4] = av.x; a_[k * 4 + 1] = av.y; a_[k * 4 + 2] = av.z; a_[k * 4 + 3] = av.w;
        c_[k * 4] = cv.x; c_[k * 4 + 1] = cv.y; c_[k * 4 + 2] = cv.z; c_[k * 4 + 3] = cv.w;
        float4 av2 = pa1[k], cv2 = pc1[k];
        a2_[k * 4] = av2.x; a2_[k * 4 + 1] = av2.y; a2_[k * 4 + 2] = av2.z; a2_[k * 4 + 3] = av2.w;
        c2_[k * 4] = cv2.x; c2_[k * 4 + 1] = cv2.y; c2_[k * 4 + 2] = cv2.z; c2_[k * 4 + 3] = cv2.w;
    }
    __syncthreads();   // rec staged

    float s[16], s2[16], hh[8], hh2[8];
#pragma unroll
    for (int e = 0; e < 16; e++) { s[e] = 0.f; s2[e] = 0.f; }
#pragma unroll
    for (int j = 0; j < 8; j++) { hh[j] = 0.f; hh2[j] = 0.f; }
    float p1_0 = 0.f, p2a_0 = 0.f, q_0 = 0.f;
    float p1_1 = 0.f, p2a_1 = 0.f, q_1 = 0.f;

    const float* recw = smem + f0 * 84;
#pragma unroll 1
    for (int i = 0; i < 16; i++) {
        const float* r = recw + i * 84;   // wave-uniform -> LDS broadcast
        float a0 = a_[i],  c0 = c_[i];
        float a1 = a2_[i], c1 = c2_[i];
        float pp0 = a0 * c0, pp1 = a1 * c1;

        float rw1 = r[78], rb1 = r[79], rb2 = r[80];
        p1_0  = fmaf(fmaf(rw1, a0, rb1), c0, p1_0);
        p1_1  = fmaf(fmaf(rw1, a1, rb1), c1, p1_1);
        p2a_0 = fmaf(a0, rb2, p2a_0);
        p2a_1 = fmaf(a1, rb2, p2a_1);

        float q0 = r[72], q1 = r[73], q2 = r[74], q3 = r[75], q4 = r[76], q5 = r[77];
        q_0 = fmaf(pp0 * pp0, q0, q_0);
        q_0 = fmaf(c0 * c0,   q1, q_0);
        q_0 = fmaf(a0 * a0,   q2, q_0);
        q_0 = fmaf(pp0 * c0,  q3, q_0);
        q_0 = fmaf(pp0 * a0,  q4, q_0);
        q_0 = fmaf(pp0,       q5, q_0);
        q_1 = fmaf(pp1 * pp1, q0, q_1);
        q_1 = fmaf(c1 * c1,   q1, q_1);
        q_1 = fmaf(a1 * a1,   q2, q_1);
        q_1 = fmaf(pp1 * c1,  q3, q_1);
        q_1 = fmaf(pp1 * a1,  q4, q_1);
        q_1 = fmaf(pp1,       q5, q_1);

#pragma unroll
        for (int e = 0; e < 16; e++) {
            float u = r[e], x = r[16 + e], y = r[32 + e];
            s[e]  = fmaf(pp0, u, fmaf(c0, x, fmaf(a0, y, s[e])));
            s2[e] = fmaf(pp1, u, fmaf(c1, x, fmaf(a1, y, s2[e])));
        }
#pragma unroll
        for (int j = 0; j < 8; j++) {
            float w1c = r[48 + j], w2c = r[56 + j], w3c = r[64 + j];
            hh[j]  = fmaf(pp0, w1c, fmaf(c0, w2c, fmaf(a0, w3c, hh[j])));
            hh2[j] = fmaf(pp1, w1c, fmaf(c1, w2c, fmaf(a1, w3c, hh2[j])));
        }
    }

    // Xc column sums over this block's 128 rows (pair-sum, then butterfly)
    {
        float cs[16];
#pragma unroll
        for (int i = 0; i < 16; i++) cs[i] = c_[i] + c2_[i];
#pragma unroll
        for (int off = 1; off < 64; off <<= 1) {
#pragma unroll
            for (int i = 0; i < 16; i++) cs[i] += __shfl_xor(cs[i], off);
        }
        if (lane == 0) {
#pragma unroll
            for (int i = 0; i < 16; i++)
                ws_blkT[(size_t)(f0 + i) * TSTR + blk] = cs[i];
        }
    }

    // ---- combine, set 0 (single 7424-float buffer; aliases rec region) ----
    __syncthreads();   // retire table reads
    {
        float* cmb = smem + (wv * 64 + lane) * 29;
#pragma unroll
        for (int e = 0; e < 16; e++) cmb[e] = s[e];
#pragma unroll
        for (int j = 0; j < 8; j++) cmb[16 + j] = hh[j];
        cmb[24] = p1_0;
        cmb[25] = p2a_0;
        cmb[26] = q_0;
    }
    __syncthreads();

    float H[8];
    float rowPartial = 0.f;
    int l_ = tid & 63;

    if (tid < 64) {   // wave 0 owns set-0 rows (blk*128 + l_)
        float S[16], P1 = 0.f, P2 = 0.f, Q = 0.f;
#pragma unroll
        for (int e = 0; e < 16; e++) S[e] = 0.f;
#pragma unroll
        for (int j = 0; j < 8; j++) H[j] = 0.f;
#pragma unroll
        for (int w = 0; w < 4; w++) {
            const float* c2 = smem + (w * 64 + l_) * 29;
#pragma unroll
            for (int e = 0; e < 16; e++) S[e] += c2[e];
#pragma unroll
            for (int j = 0; j < 8; j++) H[j] += c2[16 + j];
            P1 += c2[24];
            P2 += c2[25];
            Q  += c2[26];
        }
#pragma unroll
        for (int j = 0; j < 8; j++) H[j] += lin1_b[j];
        float ss = 0.f;
#pragma unroll
        for (int e = 0; e < 16; e++) ss = fmaf(S[e], S[e], ss);
        rowPartial = (P1 + P2) * (1.f / 64.f) + (ss - Q) * (0.5f / 16.f);

        float bn[16];
#pragma unroll
        for (int j = 0; j < 8; j++) { bn[j] = H[j]; bn[8 + j] = H[j] * H[j]; }
#pragma unroll
        for (int off = 1; off < 64; off <<= 1) {
#pragma unroll
            for (int i = 0; i < 16; i++) bn[i] += __shfl_xor(bn[i], off);
        }
        if (l_ == 0) {
#pragma unroll
            for (int i = 0; i < 16; i++)
                ws_blkT[(size_t)(64 + i) * TSTR + blk * 2] = bn[i];
        }
    }
    __syncthreads();   // retire set-0 reads

    // ---- combine, set 1 ----
    {
        float* cmb = smem + (wv * 64 + lane) * 29;
#pragma unroll
        for (int e = 0; e < 16; e++) cmb[e] = s2[e];
#pragma unroll
        for (int j = 0; j < 8; j++) cmb[16 + j] = hh2[j];
        cmb[24] = p1_1;
        cmb[25] = p2a_1;
        cmb[26] = q_1;
    }
    __syncthreads();

    if (tid >= 64 && tid < 128) {   // wave 1 owns set-1 rows (blk*128+64+l_)
        float S[16], P1 = 0.f, P2 = 0.f, Q = 0.f;
#pragma unroll
        for (int e = 0; e < 16; e++) S[e] = 0.f;
#pragma unroll
        for (int j = 0; j < 8; j++) H[j] = 0.f;
#pragma unroll
        for (int w = 0; w < 4; w++) {
            const float* c2 = smem + (w * 64 + l_) * 29;
#pragma unroll
            for (int e = 0; e < 16; e++) S[e] += c2[e];
#pragma unroll
            for (int j = 0; j < 8; j++) H[j] += c2[16 + j];
            P1 += c2[24];
            P2 += c2[25];
            Q  += c2[26];
        }
#pragma unroll
        for (int j = 0; j < 8; j++) H[j] += lin1_b[j];
        float ss = 0.f;
#pragma unroll
        for (int e = 0; e < 16; e++) ss = fmaf(S[e], S[e], ss);
        rowPartial = (P1 + P2) * (1.f / 64.f) + (ss - Q) * (0.5f / 16.f);

        float bn[16];
#pragma unroll
        for (int j = 0; j < 8; j++) { bn[j] = H[j]; bn[8 + j] = H[j] * H[j]; }
#pragma unroll
        for (int off = 1; off < 64; off <<= 1) {
#pragma unroll
            for (int i = 0; i < 16; i++) bn[i] += __shfl_xor(bn[i], off);
        }
        if (l_ == 0) {
#pragma unroll
            for (int i = 0; i < 16; i++)
                ws_blkT[(size_t)(64 + i) * TSTR + blk * 2 + 1] = bn[i];
        }
    }

    // ---- phase 2: grid-wide reduce (blocks 0..19 = 80 waves, 1 per stat) --
    grid_barrier(cnt, MBLK);
    if (blk < 20) {
        int gtid = blk * 256 + tid;
        int v  = gtid >> 6;
        int ln = gtid & 63;
        const float* p = ws_blkT + (size_t)v * TSTR + ln;
        float acc = 0.f;
        if (v < 64) {
#pragma unroll
            for (int k = 0; k < 8; k++) acc += p[k * 64];
        } else {
#pragma unroll
            for (int k = 0; k < 16; k++) acc += p[k * 64];
        }
#pragma unroll
        for (int off = 32; off; off >>= 1) acc += __shfl_xor(acc, off);
        if (ln == 0) ws_T[v] = acc;
    }
    grid_barrier(cnt, 2 * MBLK);

    // ---- phase 3: final math (smem[0..1119] reused) ----
    // smem: [0..63] sg | [64..71] scale | [72..79] shift | [80..87] colw |
    //       [88] bsum | [96..1119] qd[wave][lane][2]
    if (tid < 64) {
        smem[tid] = w2[tid] * (ws_T[tid] * (1.f / 65536.f));
    } else if (tid < 72) {
        int j = tid - 64;
        float mu  = ws_T[64 + j] * (1.f / 65536.f);
        float var = ws_T[72 + j] * (1.f / 65536.f) - mu * mu;
        float sc = gamma[j] / sqrtf(var + BN_EPS);
        smem[64 + j] = sc;
        smem[72 + j] = beta[j] - mu * sc;
    } else if (tid < 80) {
        int j = tid - 72;
        smem[80 + j] = lin2_w[j] + lin2_w[8 + j] + lin2_w[16 + j] + lin2_w[24 + j];
    } else if (tid == 80) {
        smem[88] = lin2_b[0] + lin2_b[1] + lin2_b[2] + lin2_b[3];
    }
    __syncthreads();

    // per-quarter dots from a_/a2_ (no Xa re-read)
    {
        float qd0 = 0.f, qd1 = 0.f;
#pragma unroll
        for (int i = 0; i < 16; i++) {
            float sgv = smem[f0 + i];   // wave-uniform -> LDS broadcast
            qd0 = fmaf(a_[i],  sgv, qd0);
            qd1 = fmaf(a2_[i], sgv, qd1);
        }
        smem[96 + (wv * 64 + lane) * 2]     = qd0;
        smem[96 + (wv * 64 + lane) * 2 + 1] = qd1;
    }
    __syncthreads();

    if (tid < 128) {
        int set_ = tid >> 6;
        float p2b = 0.f;
#pragma unroll
        for (int w = 0; w < 4; w++)
            p2b += smem[96 + (w * 64 + l_) * 2 + set_];
        float dmp = 0.f;
#pragma unroll
        for (int j = 0; j < 8; j++) {
            float hn = tanhf(H[j] * smem[64 + j] + smem[72 + j]);
            dmp = fmaf(hn, smem[80 + j], dmp);
        }
        int rr = blk * 128 + tid;   // tid<64: set0 row; 64..127: set1 row
        out[rr] = p2b * (1.f / 64.f) + dmp * 0.25f + rowPartial + smem[88] * 0.25f;
    }
}

extern "C" void kernel_launch(void* const* d_in, const int* in_sizes, int n_in,
                              void* d_out, int out_size, void* d_ws, size_t ws_size,
                              hipStream_t stream) {
    const float* Xa        = (const float*)d_in[0];
    const float* Xc        = (const float*)d_in[1];
    const float* w1        = (const float*)d_in[2];
    const float* b1        = (const float*)d_in[3];
    const float* w2        = (const float*)d_in[4];
    const float* b2        = (const float*)d_in[5];
    const float* W1        = (const float*)d_in[6];
    const float* B1        = (const float*)d_in[7];
    const float* W2        = (const float*)d_in[8];
    const float* B2        = (const float*)d_in[9];
    const float* lin1_w    = (const float*)d_in[10];
    const float* lin1_b    = (const float*)d_in[11];
    const float* bn1_gamma = (const float*)d_in[12];
    const float* bn1_beta  = (const float*)d_in[13];
    const float* lin2_w    = (const float*)d_in[14];
    const float* lin2_b    = (const float*)d_in[15];

    float* ws  = (float*)d_ws;
    float* out = (float*)d_out;

    float*    ws_rec  = ws + OFF_REC;
    float*    ws_blkT = ws + OFF_BLKT;
    float*    ws_T    = ws + OFF_T;
    unsigned* ws_cnt  = (unsigned*)(ws + OFF_CNT);

    precompute_kernel<<<64, 64, 0, stream>>>(W1, B1, W2, B2, lin1_w,
                                             w1, b1, b2, ws_rec, ws_cnt);
    fused_kernel<<<MBLK, 256, 0, stream>>>(Xa, Xc, ws_rec, lin1_b,
                                           w2, bn1_gamma, bn1_beta,
                                           lin2_w, lin2_b,
                                           ws_blkT, ws_T, ws_cnt, out);
}

// Round 7
// 125.117 us; speedup vs baseline: 3.2892x; 1.8905x over previous
//
#include <hip/hip_runtime.h>
#include <math.h>

#define NROWS 65536
#define BN_EPS 1e-5f
#define MBLK   512    // main-kernel grid: 128 rows per block, 2 rows/thread
#define TSTR   1024   // ws_blkT stride: colsums idx=blk (<512), BN idx=blk*2+set (<1024)

// ---- workspace layout (floats) ----
// OFF_PARTIAL : per-row partial                                        [65536]
// OFF_H       : h[row*8+j]                                             [524288]
// OFF_BLKT    : per-block stats transposed blkT[v*1024+idx], v<80      [81920]
//               v 0..63 Xc colsum (idx=blk, 512 valid)
//               v 64..71 sum h_j, 72..79 sum h_j^2 (idx=blk*2+set, 1024 valid)
// OFF_T       : reduced totals                                         [96]
#define OFF_PARTIAL 0
#define OFF_H       65536
#define OFF_BLKT    595200
#define OFF_T       677120

// 512 blocks x 256 threads, 2 rows/thread (rows row0, row0+64). R1-proven
// geometry/hot-loop (124.2 us). R6 change: precompute_kernel is DELETED --
// wave 0 builds the 84-float rec table for all 64 features directly in LDS
// (one feature per lane, straight-line port of the old per-feature math,
// ~530 FMA/lane) while the Xa/Xc float4 loads of all waves are in flight.
// Kills one launch + gap, the rec global round-trip, and the staging loop.
// R3 lesson stands: hot loop stays rolled (#pragma unroll 1) -- any full
// f-unroll spills (~1 GB scratch traffic). R5 lesson: NO manual grid
// barriers (XCD-L2 maintenance makes them ~50 us each); kernel-boundary
// sync via separate launches is cheaper.
// Colsum butterfly AFTER the hot loop (R10 lesson: shfl shares lgkmcnt).
__global__ __launch_bounds__(256)
__attribute__((amdgpu_waves_per_eu(2, 4)))
void main_kernel(
    const float* __restrict__ Xa, const float* __restrict__ Xc,
    const float* __restrict__ W1, const float* __restrict__ B1,
    const float* __restrict__ W2, const float* __restrict__ B2,
    const float* __restrict__ lin1_w, const float* __restrict__ w1,
    const float* __restrict__ b1, const float* __restrict__ b2,
    const float* __restrict__ lin1_b,
    float* __restrict__ ws_partial, float* __restrict__ ws_h,
    float* __restrict__ ws_blkT)
{
    // [0,5376) = rec[f][84] built in-LDS during phase A; then cmb[2][4][64][29]
    // (aliased, barrier-separated -- R4-proven pattern)
    __shared__ __align__(16) float smem[14848];

    int tid  = threadIdx.x;
    int lane = tid & 63;
    int wv   = tid >> 6;
    int wu   = __builtin_amdgcn_readfirstlane(wv);
    int blk  = blockIdx.x;
    int f0   = wu * 16;
    int row0 = blk * 128 + lane;
    int row1 = row0 + 64;

    // issue per-lane Xa/Xc loads FIRST (fire into registers; latency overlaps
    // the rec build below)
    const float4* pa0 = (const float4*)(Xa + (size_t)row0 * 64 + f0);
    const float4* pc0 = (const float4*)(Xc + (size_t)row0 * 64 + f0);
    const float4* pa1 = (const float4*)(Xa + (size_t)row1 * 64 + f0);
    const float4* pc1 = (const float4*)(Xc + (size_t)row1 * 64 + f0);
    float4 va0 = pa0[0], va1 = pa0[1], va2 = pa0[2], va3 = pa0[3];
    float4 vc0 = pc0[0], vc1 = pc0[1], vc2 = pc0[2], vc3 = pc0[3];
    float4 wa0 = pa1[0], wa1 = pa1[1], wa2 = pa1[2], wa3 = pa1[3];
    float4 wc0 = pc1[0], wc1 = pc1[1], wc2 = pc1[2], wc3 = pc1[3];

    // ---- in-LDS rec build: wave 0, lane f builds rec[f][0..80] ----
    // 0..15 U=W1+W2 | 16..31 B1 | 32..47 B2 | 48..55 A1 | 56..63 A2
    // 64..71 A3 | 72 QU 73 QB1 74 QB2 75 2QUB1 76 2QUB2 77 2QB1B2
    // 78 w1 79 b1 80 b2   (81..83 pads never read -> not written)
    if (tid < 64) {
        int f = tid;
        float* recf = smem + f * 84;
        float u[16], x[16], y[16];
#pragma unroll
        for (int e = 0; e < 16; e++) {
            float uu = W1[f * 16 + e] + W2[f * 16 + e];
            float xx = B1[f * 16 + e];
            float yy = B2[f * 16 + e];
            u[e] = uu; x[e] = xx; y[e] = yy;
            recf[e]      = uu;
            recf[16 + e] = xx;
            recf[32 + e] = yy;
        }
#pragma unroll 1
        for (int j = 0; j < 8; j++) {
            const float* lw = lin1_w + j * 1024 + f * 16;
            float a1 = 0.f, a2 = 0.f, a3 = 0.f;
#pragma unroll
            for (int e = 0; e < 16; e++) {
                float lv = lw[e];
                a1 = fmaf(u[e], lv, a1);
                a2 = fmaf(x[e], lv, a2);
                a3 = fmaf(y[e], lv, a3);
            }
            recf[48 + j] = a1;
            recf[56 + j] = a2;
            recf[64 + j] = a3;
        }
        {
            float quu = 0.f, qxx = 0.f, qyy = 0.f, qux = 0.f, quy = 0.f, qxy = 0.f;
#pragma unroll
            for (int e = 0; e < 16; e++) {
                float uu = u[e], xx = x[e], yy = y[e];
                quu = fmaf(uu, uu, quu);
                qxx = fmaf(xx, xx, qxx);
                qyy = fmaf(yy, yy, qyy);
                qux = fmaf(uu, xx, qux);
                quy = fmaf(uu, yy, quy);
                qxy = fmaf(xx, yy, qxy);
            }
            recf[72] = quu;
            recf[73] = qxx;
            recf[74] = qyy;
            recf[75] = 2.f * qux;
            recf[76] = 2.f * quy;
            recf[77] = 2.f * qxy;
            recf[78] = w1[f];
            recf[79] = b1[f];
            recf[80] = b2[f];
        }
    }

    // unpack a/c into the R7-proven scratch layout (waits vmcnt here)
    float a_[16], c_[16], a2_[16], c2_[16];
    a_[0]=va0.x; a_[1]=va0.y; a_[2]=va0.z; a_[3]=va0.w;
    a_[4]=va1.x; a_[5]=va1.y; a_[6]=va1.z; a_[7]=va1.w;
    a_[8]=va2.x; a_[9]=va2.y; a_[10]=va2.z; a_[11]=va2.w;
    a_[12]=va3.x; a_[13]=va3.y; a_[14]=va3.z; a_[15]=va3.w;
    c_[0]=vc0.x; c_[1]=vc0.y; c_[2]=vc0.z; c_[3]=vc0.w;
    c_[4]=vc1.x; c_[5]=vc1.y; c_[6]=vc1.z; c_[7]=vc1.w;
    c_[8]=vc2.x; c_[9]=vc2.y; c_[10]=vc2.z; c_[11]=vc2.w;
    c_[12]=vc3.x; c_[13]=vc3.y; c_[14]=vc3.z; c_[15]=vc3.w;
    a2_[0]=wa0.x; a2_[1]=wa0.y; a2_[2]=wa0.z; a2_[3]=wa0.w;
    a2_[4]=wa1.x; a2_[5]=wa1.y; a2_[6]=wa1.z; a2_[7]=wa1.w;
    a2_[8]=wa2.x; a2_[9]=wa2.y; a2_[10]=wa2.z; a2_[11]=wa2.w;
    a2_[12]=wa3.x; a2_[13]=wa3.y; a2_[14]=wa3.z; a2_[15]=wa3.w;
    c2_[0]=wc0.x; c2_[1]=wc0.y; c2_[2]=wc0.z; c2_[3]=wc0.w;
    c2_[4]=wc1.x; c2_[5]=wc1.y; c2_[6]=wc1.z; c2_[7]=wc1.w;
    c2_[8]=wc2.x; c2_[9]=wc2.y; c2_[10]=wc2.z; c2_[11]=wc2.w;
    c2_[12]=wc3.x; c2_[13]=wc3.y; c2_[14]=wc3.z; c2_[15]=wc3.w;

    __syncthreads();   // rec built

    float s[16], s2[16], hh[8], hh2[8];
#pragma unroll
    for (int e = 0; e < 16; e++) { s[e] = 0.f; s2[e] = 0.f; }
#pragma unroll
    for (int j = 0; j < 8; j++) { hh[j] = 0.f; hh2[j] = 0.f; }
    float p1_0 = 0.f, p2a_0 = 0.f, q_0 = 0.f;
    float p1_1 = 0.f, p2a_1 = 0.f, q_1 = 0.f;

    const float* recw = smem + f0 * 84;
#pragma unroll 1
    for (int i = 0; i < 16; i++) {
        const float* r = recw + i * 84;   // wave-uniform -> LDS broadcast
        float a0 = a_[i],  c0 = c_[i];
        float a1 = a2_[i], c1 = c2_[i];
        float pp0 = a0 * c0, pp1 = a1 * c1;

        float rw1 = r[78], rb1 = r[79], rb2 = r[80];
        p1_0  = fmaf(fmaf(rw1, a0, rb1), c0, p1_0);
        p1_1  = fmaf(fmaf(rw1, a1, rb1), c1, p1_1);
        p2a_0 = fmaf(a0, rb2, p2a_0);
        p2a_1 = fmaf(a1, rb2, p2a_1);

        float q0 = r[72], q1 = r[73], q2 = r[74], q3 = r[75], q4 = r[76], q5 = r[77];
        q_0 = fmaf(pp0 * pp0, q0, q_0);
        q_0 = fmaf(c0 * c0,   q1, q_0);
        q_0 = fmaf(a0 * a0,   q2, q_0);
        q_0 = fmaf(pp0 * c0,  q3, q_0);
        q_0 = fmaf(pp0 * a0,  q4, q_0);
        q_0 = fmaf(pp0,       q5, q_0);
        q_1 = fmaf(pp1 * pp1, q0, q_1);
        q_1 = fmaf(c1 * c1,   q1, q_1);
        q_1 = fmaf(a1 * a1,   q2, q_1);
        q_1 = fmaf(pp1 * c1,  q3, q_1);
        q_1 = fmaf(pp1 * a1,  q4, q_1);
        q_1 = fmaf(pp1,       q5, q_1);

#pragma unroll
        for (int e = 0; e < 16; e++) {
            float u = r[e], x = r[16 + e], y = r[32 + e];
            s[e]  = fmaf(pp0, u, fmaf(c0, x, fmaf(a0, y, s[e])));
            s2[e] = fmaf(pp1, u, fmaf(c1, x, fmaf(a1, y, s2[e])));
        }
#pragma unroll
        for (int j = 0; j < 8; j++) {
            float w1c = r[48 + j], w2c = r[56 + j], w3c = r[64 + j];
            hh[j]  = fmaf(pp0, w1c, fmaf(c0, w2c, fmaf(a0, w3c, hh[j])));
            hh2[j] = fmaf(pp1, w1c, fmaf(c1, w2c, fmaf(a1, w3c, hh2[j])));
        }
    }

    // Xc column sums over this block's 128 rows (pair-sum, then butterfly)
    {
        float cs[16];
#pragma unroll
        for (int i = 0; i < 16; i++) cs[i] = c_[i] + c2_[i];
#pragma unroll
        for (int off = 1; off < 64; off <<= 1) {
#pragma unroll
            for (int i = 0; i < 16; i++) cs[i] += __shfl_xor(cs[i], off);
        }
        if (lane == 0) {
#pragma unroll
            for (int i = 0; i < 16; i++)
                ws_blkT[(size_t)(f0 + i) * TSTR + blk] = cs[i];
        }
    }

    // cross-wave combine (aliases rec region; barrier retires table reads)
    __syncthreads();
    {
        float* cmb0 = smem + (wv * 64 + lane) * 29;
        float* cmb1 = smem + 7424 + (wv * 64 + lane) * 29;
#pragma unroll
        for (int e = 0; e < 16; e++) { cmb0[e] = s[e]; cmb1[e] = s2[e]; }
#pragma unroll
        for (int j = 0; j < 8; j++) { cmb0[16 + j] = hh[j]; cmb1[16 + j] = hh2[j]; }
        cmb0[24] = p1_0;  cmb1[24] = p1_1;
        cmb0[25] = p2a_0; cmb1[25] = p2a_1;
        cmb0[26] = q_0;   cmb1[26] = q_1;
    }
    __syncthreads();

    if (tid < 128) {
        int set = tid >> 6;        // set 0: rows +0..63 (wave 0), set 1: rows +64..127 (wave 1)
        int l   = tid & 63;
        const float* base = smem + set * 7424;
        float S[16], H[8], P1 = 0.f, P2 = 0.f, Q = 0.f;
#pragma unroll
        for (int e = 0; e < 16; e++) S[e] = 0.f;
#pragma unroll
        for (int j = 0; j < 8; j++) H[j] = 0.f;
#pragma unroll
        for (int w = 0; w < 4; w++) {
            const float* c2 = base + (w * 64 + l) * 29;
#pragma unroll
            for (int e = 0; e < 16; e++) S[e] += c2[e];
#pragma unroll
            for (int j = 0; j < 8; j++) H[j] += c2[16 + j];
            P1 += c2[24];
            P2 += c2[25];
            Q  += c2[26];
        }
#pragma unroll
        for (int j = 0; j < 8; j++) H[j] += lin1_b[j];

        float ss = 0.f;
#pragma unroll
        for (int e = 0; e < 16; e++) ss = fmaf(S[e], S[e], ss);
        int rr = blk * 128 + set * 64 + l;
        ws_partial[rr] = (P1 + P2) * (1.f / 64.f) + (ss - Q) * (0.5f / 16.f);
        *(float4*)(ws_h + (size_t)rr * 8)     = make_float4(H[0], H[1], H[2], H[3]);
        *(float4*)(ws_h + (size_t)rr * 8 + 4) = make_float4(H[4], H[5], H[6], H[7]);

        // BN partials over this set's 64 rows (butterfly stays in-wave: set==wave)
        float bn[16];
#pragma unroll
        for (int j = 0; j < 8; j++) { bn[j] = H[j]; bn[8 + j] = H[j] * H[j]; }
#pragma unroll
        for (int off = 1; off < 64; off <<= 1) {
#pragma unroll
            for (int i = 0; i < 16; i++) bn[i] += __shfl_xor(bn[i], off);
        }
        if (l == 0) {
#pragma unroll
            for (int i = 0; i < 16; i++)
                ws_blkT[(size_t)(64 + i) * TSTR + blk * 2 + set] = bn[i];
        }
    }
}

// 80 waves: one per statistic. v<64 (colsums): 512 partials; v>=64 (BN): 1024.
__global__ __launch_bounds__(256) void reduce_kernel(
    const float* __restrict__ ws_blkT, float* __restrict__ T)
{
    int gtid = blockIdx.x * 256 + threadIdx.x;
    int v = gtid >> 6;
    int lane = gtid & 63;
    const float* p = ws_blkT + (size_t)v * TSTR + lane;
    float acc = 0.f;
    if (v < 64) {
#pragma unroll
        for (int k = 0; k < 8; k++) acc += p[k * 64];
    } else {
#pragma unroll
        for (int k = 0; k < 16; k++) acc += p[k * 64];
    }
#pragma unroll
    for (int off = 32; off; off >>= 1) acc += __shfl_xor(acc, off);
    if (lane == 0) T[v] = acc;
}

// 512 blocks x 256 threads: two threads per row. (R8-proven)
__global__ __launch_bounds__(256) void final_kernel(
    const float* __restrict__ Xa, const float* __restrict__ w2,
    const float* __restrict__ gamma, const float* __restrict__ beta,
    const float* __restrict__ lin2_w, const float* __restrict__ lin2_b,
    const float* __restrict__ T, const float* __restrict__ ws_partial,
    const float* __restrict__ ws_h, float* __restrict__ out)
{
    __shared__ float sg[64], sScale[8], sShift[8], sColw[8];
    __shared__ float sBsum;
    int tid = threadIdx.x;
    if (tid < 64) {
        sg[tid] = w2[tid] * (T[tid] * (1.f / 65536.f));
    } else if (tid < 72) {
        int j = tid - 64;
        float mu  = T[64 + j] * (1.f / 65536.f);
        float var = T[72 + j] * (1.f / 65536.f) - mu * mu;
        float sc = gamma[j] / sqrtf(var + BN_EPS);
        sScale[j] = sc;
        sShift[j] = beta[j] - mu * sc;
    } else if (tid < 80) {
        int j = tid - 72;
        sColw[j] = lin2_w[j] + lin2_w[8 + j] + lin2_w[16 + j] + lin2_w[24 + j];
    } else if (tid == 80) {
        sBsum = lin2_b[0] + lin2_b[1] + lin2_b[2] + lin2_b[3];
    }
    __syncthreads();

    int row  = (blockIdx.x * 256 + tid) >> 1;
    int half = tid & 1;
    int fo   = half * 32;

    const float4* xa4 = (const float4*)(Xa + (size_t)row * 64 + fo);
    float p2b = 0.f;
#pragma unroll
    for (int k = 0; k < 8; k++) {
        float4 vv = xa4[k];
        int b = fo + k * 4;
        p2b += vv.x * sg[b] + vv.y * sg[b + 1] + vv.z * sg[b + 2] + vv.w * sg[b + 3];
    }

    float4 hq = *(const float4*)(ws_h + (size_t)row * 8 + half * 4);
    float hv[4] = {hq.x, hq.y, hq.z, hq.w};
    float dmp = 0.f;
#pragma unroll
    for (int jj = 0; jj < 4; jj++) {
        int j = half * 4 + jj;
        float hn = tanhf(hv[jj] * sScale[j] + sShift[j]);
        dmp = fmaf(hn, sColw[j], dmp);
    }

    float val = p2b * (1.f / 64.f) + dmp * 0.25f;
    val += __shfl_xor(val, 1);
    if (!half)
        out[row] = val + ws_partial[row] + sBsum * 0.25f;
}

extern "C" void kernel_launch(void* const* d_in, const int* in_sizes, int n_in,
                              void* d_out, int out_size, void* d_ws, size_t ws_size,
                              hipStream_t stream) {
    const float* Xa        = (const float*)d_in[0];
    const float* Xc        = (const float*)d_in[1];
    const float* w1        = (const float*)d_in[2];
    const float* b1        = (const float*)d_in[3];
    const float* w2        = (const float*)d_in[4];
    const float* b2        = (const float*)d_in[5];
    const float* W1        = (const float*)d_in[6];
    const float* B1        = (const float*)d_in[7];
    const float* W2        = (const float*)d_in[8];
    const float* B2        = (const float*)d_in[9];
    const float* lin1_w    = (const float*)d_in[10];
    const float* lin1_b    = (const float*)d_in[11];
    const float* bn1_gamma = (const float*)d_in[12];
    const float* bn1_beta  = (const float*)d_in[13];
    const float* lin2_w    = (const float*)d_in[14];
    const float* lin2_b    = (const float*)d_in[15];

    float* ws  = (float*)d_ws;
    float* out = (float*)d_out;

    float* ws_partial = ws + OFF_PARTIAL;
    float* ws_h       = ws + OFF_H;
    float* ws_blkT    = ws + OFF_BLKT;
    float* ws_T       = ws + OFF_T;

    main_kernel<<<MBLK, 256, 0, stream>>>(Xa, Xc, W1, B1, W2, B2, lin1_w,
                                          w1, b1, b2, lin1_b,
                                          ws_partial, ws_h, ws_blkT);
    reduce_kernel<<<20, 256, 0, stream>>>(ws_blkT, ws_T);
    final_kernel<<<512, 256, 0, stream>>>(Xa, w2, bn1_gamma, bn1_beta,
                                          lin2_w, lin2_b, ws_T,
                                          ws_partial, ws_h, out);
}